// Round 1
// baseline (440.160 us; speedup 1.0000x reference)
//
#include <hip/hip_runtime.h>
#include <hip/hip_bf16.h>

// Problem: B=1, L=768, D_SINGLE=384, D_PAIR=128
//   left  = s @ W[:384]    (768 x 128)
//   right = s @ W[384:]    (768 x 128)
//   out[i,j,f] = left[i,f] + right[j,f] + bias[f]   -> (1,768,768,128) fp32
// z (d_in[1]) is UNUSED by the reference.

#define L_DIM   768
#define D_S     384
#define D_P     128

// ---------------- Kernel A: projection -------------------------------------
// grid = (768), block = (256). blockIdx.x = row l. threadIdx.x = f in [0,256).
// proj[l*256 + f]       = left[l][f]  + bias[f]   (f < 128)
// proj[l*256 + 128 + f] = right[l][f]             (f >= 128)
__global__ __launch_bounds__(256) void proj_kernel(
    const float* __restrict__ s,     // (768, 384)
    const float* __restrict__ W,     // (768, 128)
    const float* __restrict__ bias,  // (128,)
    float* __restrict__ proj)        // (768, 256)
{
    __shared__ float s_row[D_S];
    const int l = blockIdx.x;
    const int f = threadIdx.x;

    // stage s row (1.5 KB) into LDS, coalesced
    for (int d = threadIdx.x; d < D_S; d += 256) s_row[d] = s[l * D_S + d];
    __syncthreads();

    const int fc = f & (D_P - 1);
    const float* Wbase = W + ((f >= D_P) ? (D_S * D_P) : 0) + fc;

    float acc = (f < D_P) ? bias[fc] : 0.0f;  // fold bias into left only
#pragma unroll 8
    for (int d = 0; d < D_S; ++d) {
        acc = fmaf(s_row[d], Wbase[(size_t)d * D_P], acc);
    }
    proj[l * 256 + f] = acc;
}

// ---------------- Kernel B: outer broadcast sum ----------------------------
// grid = (96, 768), block = 256. blockIdx.y = i.
// t = blockIdx.x*256 + tid in [0, 768*32): f4 = t & 31, j = t >> 5.
// out4[i*24576 + t] = left4[i][f4] + right4[j][f4]
__global__ __launch_bounds__(256) void outer_kernel(
    const float4* __restrict__ proj4,  // (768, 64) float4 view of proj
    float4* __restrict__ out4)         // (768*768*32) float4
{
    const int i  = blockIdx.y;
    const int t  = blockIdx.x * 256 + threadIdx.x;  // [0, 24576)
    const int f4 = t & 31;
    const int j  = t >> 5;

    const float4 lv = proj4[i * 64 + f4];        // left row, L1-broadcast
    const float4 rv = proj4[j * 64 + 32 + f4];   // right row

    float4 o;
    o.x = lv.x + rv.x;
    o.y = lv.y + rv.y;
    o.z = lv.z + rv.z;
    o.w = lv.w + rv.w;

    out4[(size_t)i * (L_DIM * (D_P / 4)) + t] = o;
}

extern "C" void kernel_launch(void* const* d_in, const int* in_sizes, int n_in,
                              void* d_out, int out_size, void* d_ws, size_t ws_size,
                              hipStream_t stream) {
    const float* s    = (const float*)d_in[0];
    // d_in[1] = z, unused by the reference
    const float* W    = (const float*)d_in[2];
    const float* bias = (const float*)d_in[3];
    float* out  = (float*)d_out;
    float* proj = (float*)d_ws;   // 768*256 floats = 786 KB

    proj_kernel<<<dim3(L_DIM), dim3(256), 0, stream>>>(s, W, bias, proj);

    outer_kernel<<<dim3(L_DIM * (D_P / 4) / 256, L_DIM), dim3(256), 0, stream>>>(
        (const float4*)proj, (float4*)out);
}